// Round 3
// baseline (525.325 us; speedup 1.0000x reference)
//
#include <hip/hip_runtime.h>
#include <math.h>

// Problem constants
#define N_ROWS 8192
#define M_COLS 2048
#define K_DIM  1024
#define NM     ((size_t)N_ROWS * M_COLS)

#define LAM       0.9090909090909091f         // GAMMA/(GAMMA+EPS)
#define LOG_M     7.624618986159398f          // log(2048)

#define SKB 512                                // sinkhorn blocks
#define RPB (N_ROWS / SKB)                     // 16 rows per block

typedef __bf16 bf16x8 __attribute__((ext_vector_type(8)));
typedef float  f32x4  __attribute__((ext_vector_type(4)));
typedef unsigned short u16x8 __attribute__((ext_vector_type(8)));
typedef _Float16 h8 __attribute__((ext_vector_type(8)));

// d_out memory map (64 MB):
//   row r (r<8192): bytes [r*8192, r*8192+4096)  = cost fp16 row r (2048 halves)
//                   bytes [r*8192+4096, r*8192+8192) = "hole"
//   Xb bf16 row i (16 MB): hole i>>1, slot i&1  -> byte (i>>1)*8192 + 4096 + (i&1)*2048
//   Yb bf16 row j ( 4 MB): hole 4096+(j>>1)     -> byte 32MB + (j>>1)*8192 + 4096 + (j&1)*2048
// GEMM writes cost into even chunks while reading Xb/Yb from odd chunks (disjoint).
// E = exp(-10*cost/cmax) is recomputed in registers by every sinkhorn pass —
// it is never materialized in memory.

static __device__ __forceinline__ size_t xb_off(int i) {
    return ((size_t)(i >> 1) << 13) + 4096 + ((size_t)(i & 1) << 11);
}
static __device__ __forceinline__ size_t yb_off(int j) {
    return ((size_t)1 << 25) + ((size_t)(j >> 1) << 13) + 4096 + ((size_t)(j & 1) << 11);
}

// ---------------------------------------------------------------------------
// fp32 pair -> packed bf16 (RNE)
// ---------------------------------------------------------------------------
static __device__ __forceinline__ unsigned pk_bf16(float a, float b) {
#if __has_builtin(__builtin_amdgcn_cvt_pk_bf16_f32)
    typedef __bf16 bf16x2 __attribute__((ext_vector_type(2)));
    bf16x2 r = __builtin_amdgcn_cvt_pk_bf16_f32(a, b);
    return __builtin_bit_cast(unsigned, r);
#else
    unsigned ua = __float_as_uint(a), ub = __float_as_uint(b);
    ua += 0x7FFFu + ((ua >> 16) & 1u);
    ub += 0x7FFFu + ((ub >> 16) & 1u);
    return (ua >> 16) | (ub & 0xFFFF0000u);
#endif
}

static __device__ __forceinline__ bf16x8 lds_frag(const unsigned short* p) {
    return __builtin_bit_cast(bf16x8, *(const u16x8*)p);
}

static __device__ __forceinline__ void gload16(const void* g, void* l) {
    __builtin_amdgcn_global_load_lds(
        (const __attribute__((address_space(1))) unsigned int*)g,
        (__attribute__((address_space(3))) unsigned int*)l, 16, 0, 0);
}

// ---------------------------------------------------------------------------
// per-row stats (min, sum, ||a-min||^2) + bf16 conversion into d_out holes.
// blocks 0..8191 = X rows; 8192..10239 = Y rows. 256 thr, 4 cols each.
// Block 0 additionally does the old k_init work (params, sigma=0, d2max=0,
// dist=0) — stream order guarantees visibility to the GEMM and sk passes.
// ---------------------------------------------------------------------------
__global__ __launch_bounds__(256) void rowstats_cvt(
    const float* __restrict__ X, const float* __restrict__ Y,
    unsigned char* __restrict__ outb,
    const int* __restrict__ iters, const int* __restrict__ ipe,
    float* __restrict__ params, float* __restrict__ sigma,
    unsigned int* __restrict__ d2max, float* __restrict__ dist,
    float* __restrict__ mx, float* __restrict__ sx, float* __restrict__ x2,
    float* __restrict__ my, float* __restrict__ sy, float* __restrict__ y2)
{
    const int b = blockIdx.x, tid = threadIdx.x;

    if (b == 0) {
        #pragma unroll 1
        for (int i = tid; i < 3 * M_COLS; i += 256) sigma[i] = 0.0f;
        if (tid == 0) {
            float ramp = 10.0f * (float)ipe[0];
            float rho;
            if (ramp == 0.0f) {
                rho = 1.1f;
            } else {
                float cur = fminf(fmaxf((float)iters[0], 0.0f), ramp);
                float phase = 1.0f - cur / ramp;
                rho = expf(-5.0f * phase * phase) + 0.1f;
            }
            rho = fminf(rho, 1.0f);
            params[0] = rho;
            params[1] = logf(rho) - LOG_M;   // logb = log(rho/M)
            *d2max = 0u;
            *dist = 0.0f;
        }
    }

    const bool isX = b < N_ROWS;
    const int row = isX ? b : b - N_ROWS;
    const float* src = isX ? (X + (size_t)row * K_DIM) : (Y + (size_t)row * K_DIM);
    const float4 v = ((const float4*)src)[tid];

    // bf16 convert into hole
    uint2 p; p.x = pk_bf16(v.x, v.y); p.y = pk_bf16(v.z, v.w);
    size_t off = isX ? xb_off(row) : yb_off(row);
    *(uint2*)(outb + off + (size_t)tid * 8) = p;

    float lmin = fminf(fminf(v.x, v.y), fminf(v.z, v.w));
    float lsum = v.x + v.y + v.z + v.w;
    float lsq  = v.x*v.x + v.y*v.y + v.z*v.z + v.w*v.w;

    __shared__ float rmin[256], rsum[256], rsq[256];
    rmin[tid] = lmin; rsum[tid] = lsum; rsq[tid] = lsq;
    __syncthreads();
    for (int s = 128; s > 0; s >>= 1) {
        if (tid < s) {
            rmin[tid] = fminf(rmin[tid], rmin[tid + s]);
            rsum[tid] += rsum[tid + s];
            rsq[tid]  += rsq[tid + s];
        }
        __syncthreads();
    }
    if (tid == 0) {
        float m = rmin[0], s = rsum[0], q = rsq[0];
        if (isX) { mx[row] = m; sx[row] = s; x2[row] = q - 2.f*m*s + (float)K_DIM*m*m; }
        else     { my[row] = m; sy[row] = s; y2[row] = q - 2.f*m*s + (float)K_DIM*m*m; }
    }
}

// ---------------------------------------------------------------------------
// MFMA GEMM on pre-converted bf16 + cost epilogue (fp16 store).
// 128x128 tile, 4 waves (2x2 of 64x64), BK=32, global_load_lds width 16.
// 2-phase double-buffered K-loop; XCD-swizzled block id.  (verified round 1)
// ---------------------------------------------------------------------------
__global__ __launch_bounds__(256, 4) void gemm_cost_mfma(
    float* __restrict__ gbuf,
    const float* __restrict__ mx, const float* __restrict__ sx, const float* __restrict__ x2,
    const float* __restrict__ my, const float* __restrict__ sy, const float* __restrict__ y2,
    unsigned int* __restrict__ d2max)
{
    __shared__ unsigned short Ash[2][128 * 32];   // 2 x 8 KB
    __shared__ unsigned short Bsh[2][128 * 32];   // 2 x 8 KB
    __shared__ float rmax[256];

    const unsigned char* outb = (const unsigned char*)gbuf;
    const int tid   = threadIdx.x;
    const int lane  = tid & 63;
    const int wave  = tid >> 6;
    const int wi    = wave >> 1;          // 0..1
    const int wj    = wave & 1;           // 0..1
    const int row16 = lane & 15;
    const int quad  = lane >> 4;          // 0..3

    // XCD-aware swizzle (bijective: 1024 blocks, 1024%8==0).
    const int bid0 = blockIdx.y * 16 + blockIdx.x;
    const int bid  = (bid0 & 7) * 128 + (bid0 >> 3);
    const int i0 = (bid >> 4) * 128, j0 = (bid & 15) * 128;

    const int chA = (lane & 3) * 16;       // byte chunk within 64 B row
    const unsigned char* pa[2];
    const unsigned char* pb[2];
    unsigned short* laA[2];
    unsigned short* lbB[2];
    #pragma unroll
    for (int p = 0; p < 2; ++p) {
        const int rt = (p * 4 + wave) * 16 + (lane >> 2);   // row in tile
        pa[p] = outb + xb_off(i0 + rt) + chA;
        pb[p] = outb + yb_off(j0 + rt) + chA;
        laA[p] = &Ash[0][(p * 4 + wave) * 512];
        lbB[p] = &Bsh[0][(p * 4 + wave) * 512];
    }

    f32x4 acc[4][4];
    #pragma unroll
    for (int u = 0; u < 4; ++u)
        #pragma unroll
        for (int v = 0; v < 4; ++v) acc[u][v] = (f32x4){0.f, 0.f, 0.f, 0.f};

#define STAGE(nb) do {                                        \
        gload16(pa[0], laA[0] + (nb) * 4096);                 \
        gload16(pa[1], laA[1] + (nb) * 4096);                 \
        gload16(pb[0], lbB[0] + (nb) * 4096);                 \
        gload16(pb[1], lbB[1] + (nb) * 4096);                 \
        pa[0] += 64; pa[1] += 64; pb[0] += 64; pb[1] += 64;   \
    } while (0)

#define COMPUTE(cb) do {                                                         \
        bf16x8 af[4], bfr[4];                                                    \
        _Pragma("unroll")                                                        \
        for (int t = 0; t < 4; ++t) {                                            \
            af[t]  = lds_frag(&Ash[cb][(wi * 64 + t * 16 + row16) * 32 + quad * 8]); \
            bfr[t] = lds_frag(&Bsh[cb][(wj * 64 + t * 16 + row16) * 32 + quad * 8]); \
        }                                                                        \
        _Pragma("unroll")                                                        \
        for (int ti = 0; ti < 4; ++ti)                                           \
            _Pragma("unroll")                                                    \
            for (int tj = 0; tj < 4; ++tj)                                       \
                acc[ti][tj] = __builtin_amdgcn_mfma_f32_16x16x32_bf16(           \
                    af[ti], bfr[tj], acc[ti][tj], 0, 0, 0);                      \
    } while (0)

    STAGE(0);
    __syncthreads();

#pragma unroll 1
    for (int it = 0; it < 15; ++it) {
        STAGE(1); COMPUTE(0); __syncthreads();
        STAGE(0); COMPUTE(1); __syncthreads();
    }
    STAGE(1); COMPUTE(0); __syncthreads();
    COMPUTE(1);

#undef STAGE
#undef COMPUTE

    // epilogue: C/D layout col=lane&15 (j), row=quad*4+reg (i); store fp16 cost
    _Float16* costh = (_Float16*)gbuf;
    float lmax = 0.0f;
    float myj[4], syj[4], yy[4];
    #pragma unroll
    for (int tj = 0; tj < 4; ++tj) {
        const int j = j0 + wj * 64 + tj * 16 + row16;
        myj[tj] = my[j]; syj[tj] = sy[j]; yy[tj] = y2[j];
    }
    #pragma unroll
    for (int ti = 0; ti < 4; ++ti) {
        #pragma unroll
        for (int reg = 0; reg < 4; ++reg) {
            const int i = i0 + wi * 64 + ti * 16 + quad * 4 + reg;
            const float mxi = mx[i], sxi = sx[i], xxi = x2[i];
            #pragma unroll
            for (int tj = 0; tj < 4; ++tj) {
                const int j = j0 + wj * 64 + tj * 16 + row16;
                float corr = mxi * syj[tj] + myj[tj] * sxi - (float)K_DIM * mxi * myj[tj];
                float d2 = xxi + yy[tj] - 2.0f * acc[ti][tj][reg] + 2.0f * corr;
                d2 = fmaxf(d2, 0.0f);
                lmax = fmaxf(lmax, d2);
                costh[(size_t)i * 4096 + j] = (_Float16)sqrtf(d2);
            }
        }
    }
    rmax[tid] = lmax;
    __syncthreads();
    for (int s = 128; s > 0; s >>= 1) {
        if (tid < s) rmax[tid] = fmaxf(rmax[tid], rmax[tid + s]);
        __syncthreads();
    }
    if (tid == 0) atomicMax(d2max, __float_as_uint(rmax[0]));
}

// ---------------------------------------------------------------------------
// Sinkhorn pass IT (0,1,2). Reads cost fp16, recomputes E in registers:
//   E = exp(-cost * 10/cmax)   (fp16-rounded, matching verified numerics)
//   u_j = 1 (IT=0) or N/sigma[IT-1][j]
//   t_r = sum_j E u_j ; w_r = exp(-LAM*(logb + ln t_r))   (w stored at IT=2)
//   sigma[IT][j] += sum_r E w_r   via fp32 atomicAdd (each thread owns 8 cols)
// 512 blocks x 256 threads; block = 16 rows; thread = 8 contiguous cols.
// ---------------------------------------------------------------------------
template<int IT>
__global__ __launch_bounds__(256) void sk_pass(
    const float* __restrict__ outbuf, float* __restrict__ sigma,
    float* __restrict__ w,
    const float* __restrict__ params, const unsigned int* __restrict__ d2max)
{
    const int tid  = threadIdx.x;
    const int lane = tid & 63;
    const int wave = tid >> 6;
    const int r0   = blockIdx.x * RPB;
    const float logb = params[1];
    const float invC10 = 10.0f * rsqrtf(__uint_as_float(*d2max));

    const _Float16* Eb = (const _Float16*)outbuf;
    h8 E[RPB];
    #pragma unroll
    for (int r = 0; r < RPB; ++r) {
        h8 c = __builtin_bit_cast(h8, *(const uint4*)(Eb + (size_t)(r0 + r) * 4096 + 8 * tid));
        h8 e;
        #pragma unroll
        for (int k = 0; k < 8; ++k)
            e[k] = (_Float16)__expf(-(float)c[k] * invC10);
        E[r] = e;
    }

    float u8[8];
    if constexpr (IT == 0) {
        #pragma unroll
        for (int c = 0; c < 8; ++c) u8[c] = 1.0f;
    } else {
        const float* sg = sigma + (IT - 1) * M_COLS;
        const float4 sa = *(const float4*)(sg + 8 * tid);
        const float4 sb = *(const float4*)(sg + 8 * tid + 4);
        u8[0] = (float)N_ROWS / sa.x; u8[1] = (float)N_ROWS / sa.y;
        u8[2] = (float)N_ROWS / sa.z; u8[3] = (float)N_ROWS / sa.w;
        u8[4] = (float)N_ROWS / sb.x; u8[5] = (float)N_ROWS / sb.y;
        u8[6] = (float)N_ROWS / sb.z; u8[7] = (float)N_ROWS / sb.w;
    }

    // pass A: row sums t_r
    float pr[RPB];
    #pragma unroll
    for (int r = 0; r < RPB; ++r) {
        float s = 0.0f;
        #pragma unroll
        for (int c = 0; c < 8; ++c) s += (float)E[r][c] * u8[c];
        pr[r] = s;
    }
    #pragma unroll
    for (int r = 0; r < RPB; ++r)
        #pragma unroll
        for (int off = 32; off > 0; off >>= 1)
            pr[r] += __shfl_xor(pr[r], off, 64);

    __shared__ float R[RPB][4];
    __shared__ float W[RPB];
    if (lane == 0)
        #pragma unroll
        for (int r = 0; r < RPB; ++r) R[r][wave] = pr[r];
    __syncthreads();
    if (tid < RPB) {
        float t = R[tid][0] + R[tid][1] + R[tid][2] + R[tid][3];
        float wr = __expf(-LAM * (logb + __logf(t)));
        W[tid] = wr;
        if constexpr (IT == 2) w[r0 + tid] = wr;
    }
    __syncthreads();

    // pass B: column partials -> fp32 atomicAdd into sigma[IT]
    float p[8] = {0.f, 0.f, 0.f, 0.f, 0.f, 0.f, 0.f, 0.f};
    #pragma unroll
    for (int r = 0; r < RPB; ++r) {
        const float wr = W[r];
        #pragma unroll
        for (int c = 0; c < 8; ++c) p[c] += (float)E[r][c] * wr;
    }
    float* sg1 = sigma + IT * M_COLS;
    #pragma unroll
    for (int c = 0; c < 8; ++c) atomicAdd(&sg1[8 * tid + c], p[c]);
}

// ---------------------------------------------------------------------------
// flow = E * w_r * u_j / (N*M)  (in-place: fp16 cost rows -> fp32 flow rows)
// dist += sum cn * flow,  cn = cost/cmax (direct — no log);  u_j = N/sigma2_j
// All cost rows loaded to registers, ONE barrier (drains vmcnt), then stores.
// ---------------------------------------------------------------------------
__global__ __launch_bounds__(256) void flow_dist(
    float* __restrict__ outbuf, const float* __restrict__ w,
    const float* __restrict__ sigma2, const unsigned int* __restrict__ d2max,
    float* __restrict__ dist)
{
    const int tid = threadIdx.x;
    const int r0  = blockIdx.x * RPB;
    const float invNM = 1.0f / ((float)N_ROWS * (float)M_COLS);
    const float invC10 = 10.0f * rsqrtf(__uint_as_float(*d2max));
    const float inv01  = 0.1f * invC10;          // = 1/cmax
    const _Float16* Eb = (const _Float16*)outbuf;

    h8 C[RPB];
    #pragma unroll
    for (int r = 0; r < RPB; ++r)
        C[r] = __builtin_bit_cast(h8, *(const uint4*)(Eb + (size_t)(r0 + r) * 4096 + 8 * tid));

    __shared__ float W[RPB];
    if (tid < RPB) W[tid] = w[r0 + tid];

    const float4 sA = *(const float4*)(sigma2 + 8 * tid);
    const float4 sB = *(const float4*)(sigma2 + 8 * tid + 4);
    float u8[8];
    u8[0] = (float)N_ROWS / sA.x; u8[1] = (float)N_ROWS / sA.y;
    u8[2] = (float)N_ROWS / sA.z; u8[3] = (float)N_ROWS / sA.w;
    u8[4] = (float)N_ROWS / sB.x; u8[5] = (float)N_ROWS / sB.y;
    u8[6] = (float)N_ROWS / sB.z; u8[7] = (float)N_ROWS / sB.w;

    __syncthreads();   // drains all cost loads + publishes W before any store

    float local = 0.0f;
    #pragma unroll
    for (int r = 0; r < RPB; ++r) {
        const float wr = W[r];
        float fl[8];
        #pragma unroll
        for (int c = 0; c < 8; ++c) {
            float cst = (float)C[r][c];
            float e = __expf(-cst * invC10);
            float o = e * wr * u8[c] * invNM;
            fl[c] = o;
            local += (cst * inv01) * o;
        }
        float4 o0 = {fl[0], fl[1], fl[2], fl[3]};
        float4 o1 = {fl[4], fl[5], fl[6], fl[7]};
        float* frow = outbuf + (size_t)(r0 + r) * M_COLS + 8 * tid;
        *(float4*)frow = o0;
        *(float4*)(frow + 4) = o1;
    }

    __shared__ float red[256];
    red[tid] = local;
    __syncthreads();
    for (int s = 128; s > 0; s >>= 1) {
        if (tid < s) red[tid] += red[tid + s];
        __syncthreads();
    }
    if (tid == 0) atomicAdd(dist, red[0]);
}

// ---------------------------------------------------------------------------
extern "C" void kernel_launch(void* const* d_in, const int* in_sizes, int n_in,
                              void* d_out, int out_size, void* d_ws, size_t ws_size,
                              hipStream_t stream)
{
    const float* x     = (const float*)d_in[0];
    const float* y     = (const float*)d_in[1];
    const int*   iters = (const int*)d_in[2];
    const int*   ipe   = (const int*)d_in[3];
    float* out = (float*)d_out;
    float* ws  = (float*)d_ws;

    // ws layout (floats)
    float*        params = ws;                       // [0]=rho [1]=logb
    unsigned int* d2max  = (unsigned int*)(ws + 8);
    float* w     = ws + 16;                          // 8192
    float* sigma = w + N_ROWS;                       // 3 * 2048 (zeroed by rowstats blk0)
    float* mx = sigma + 3 * M_COLS;                  // 8192
    float* sx = mx + N_ROWS;                         // 8192
    float* x2 = sx + N_ROWS;                         // 8192
    float* my = x2 + N_ROWS;                         // 2048
    float* sy = my + M_COLS;                         // 2048
    float* y2 = sy + M_COLS;                         // 2048

    float* dist = out + NM;

    rowstats_cvt<<<N_ROWS + M_COLS, 256, 0, stream>>>(
        x, y, (unsigned char*)out, iters, ipe, params, sigma, d2max, dist,
        mx, sx, x2, my, sy, y2);
    gemm_cost_mfma<<<dim3(M_COLS / 128, N_ROWS / 128), 256, 0, stream>>>(
        out, mx, sx, x2, my, sy, y2, d2max);

    sk_pass<0><<<SKB, 256, 0, stream>>>(out, sigma, w, params, d2max);
    sk_pass<1><<<SKB, 256, 0, stream>>>(out, sigma, w, params, d2max);
    sk_pass<2><<<SKB, 256, 0, stream>>>(out, sigma, w, params, d2max);

    flow_dist<<<SKB, 256, 0, stream>>>(out, w, sigma + 2 * M_COLS, d2max, dist);
}

// Round 4
// 519.597 us; speedup vs baseline: 1.0110x; 1.0110x over previous
//
#include <hip/hip_runtime.h>
#include <math.h>

// Problem constants
#define N_ROWS 8192
#define M_COLS 2048
#define K_DIM  1024
#define NM     ((size_t)N_ROWS * M_COLS)

#define LAM       0.9090909090909091f         // GAMMA/(GAMMA+EPS)
#define LOG_M     7.624618986159398f          // log(2048)

#define SKB 512                                // sinkhorn blocks
#define RPB (N_ROWS / SKB)                     // 16 rows per block

typedef __bf16 bf16x8 __attribute__((ext_vector_type(8)));
typedef float  f32x4  __attribute__((ext_vector_type(4)));
typedef unsigned short u16x8 __attribute__((ext_vector_type(8)));
typedef _Float16 h8 __attribute__((ext_vector_type(8)));

// d_out memory map (64 MB):
//   row r (r<8192): bytes [r*8192, r*8192+4096)  = cost fp16 row r (2048 halves)
//                   bytes [r*8192+4096, r*8192+8192) = "hole"
//   Xb bf16 row i (16 MB): hole i>>1, slot i&1  -> byte (i>>1)*8192 + 4096 + (i&1)*2048
//   Yb bf16 row j ( 4 MB): hole 4096+(j>>1)     -> byte 32MB + (j>>1)*8192 + 4096 + (j&1)*2048
// GEMM writes cost into even chunks while reading Xb/Yb from odd chunks (disjoint).
// E = exp(-10*cost/cmax) is recomputed per sinkhorn pass; per-block working set
// (16 rows x 2048 fp16 = 64 KB) is staged in LDS — NEVER in a big register
// array (round-3 lesson: the compiler spills it to scratch = 66 MB of HBM).

static __device__ __forceinline__ size_t xb_off(int i) {
    return ((size_t)(i >> 1) << 13) + 4096 + ((size_t)(i & 1) << 11);
}
static __device__ __forceinline__ size_t yb_off(int j) {
    return ((size_t)1 << 25) + ((size_t)(j >> 1) << 13) + 4096 + ((size_t)(j & 1) << 11);
}

// ---------------------------------------------------------------------------
// fp32 pair -> packed bf16 (RNE)
// ---------------------------------------------------------------------------
static __device__ __forceinline__ unsigned pk_bf16(float a, float b) {
#if __has_builtin(__builtin_amdgcn_cvt_pk_bf16_f32)
    typedef __bf16 bf16x2 __attribute__((ext_vector_type(2)));
    bf16x2 r = __builtin_amdgcn_cvt_pk_bf16_f32(a, b);
    return __builtin_bit_cast(unsigned, r);
#else
    unsigned ua = __float_as_uint(a), ub = __float_as_uint(b);
    ua += 0x7FFFu + ((ua >> 16) & 1u);
    ub += 0x7FFFu + ((ub >> 16) & 1u);
    return (ua >> 16) | (ub & 0xFFFF0000u);
#endif
}

static __device__ __forceinline__ bf16x8 lds_frag(const unsigned short* p) {
    return __builtin_bit_cast(bf16x8, *(const u16x8*)p);
}

static __device__ __forceinline__ void gload16(const void* g, void* l) {
    __builtin_amdgcn_global_load_lds(
        (const __attribute__((address_space(1))) unsigned int*)g,
        (__attribute__((address_space(3))) unsigned int*)l, 16, 0, 0);
}

// ---------------------------------------------------------------------------
// per-row stats (min, sum, ||a-min||^2) + bf16 conversion into d_out holes.
// blocks 0..8191 = X rows; 8192..10239 = Y rows. 256 thr, 4 cols each.
// Block 0 additionally does init (params, sigma=0, d2max=0, dist=0).
// ---------------------------------------------------------------------------
__global__ __launch_bounds__(256) void rowstats_cvt(
    const float* __restrict__ X, const float* __restrict__ Y,
    unsigned char* __restrict__ outb,
    const int* __restrict__ iters, const int* __restrict__ ipe,
    float* __restrict__ params, float* __restrict__ sigma,
    unsigned int* __restrict__ d2max, float* __restrict__ dist,
    float* __restrict__ mx, float* __restrict__ sx, float* __restrict__ x2,
    float* __restrict__ my, float* __restrict__ sy, float* __restrict__ y2)
{
    const int b = blockIdx.x, tid = threadIdx.x;

    if (b == 0) {
        #pragma unroll 1
        for (int i = tid; i < 3 * M_COLS; i += 256) sigma[i] = 0.0f;
        if (tid == 0) {
            float ramp = 10.0f * (float)ipe[0];
            float rho;
            if (ramp == 0.0f) {
                rho = 1.1f;
            } else {
                float cur = fminf(fmaxf((float)iters[0], 0.0f), ramp);
                float phase = 1.0f - cur / ramp;
                rho = expf(-5.0f * phase * phase) + 0.1f;
            }
            rho = fminf(rho, 1.0f);
            params[0] = rho;
            params[1] = logf(rho) - LOG_M;   // logb = log(rho/M)
            *d2max = 0u;
            *dist = 0.0f;
        }
    }

    const bool isX = b < N_ROWS;
    const int row = isX ? b : b - N_ROWS;
    const float* src = isX ? (X + (size_t)row * K_DIM) : (Y + (size_t)row * K_DIM);
    const float4 v = ((const float4*)src)[tid];

    // bf16 convert into hole
    uint2 p; p.x = pk_bf16(v.x, v.y); p.y = pk_bf16(v.z, v.w);
    size_t off = isX ? xb_off(row) : yb_off(row);
    *(uint2*)(outb + off + (size_t)tid * 8) = p;

    float lmin = fminf(fminf(v.x, v.y), fminf(v.z, v.w));
    float lsum = v.x + v.y + v.z + v.w;
    float lsq  = v.x*v.x + v.y*v.y + v.z*v.z + v.w*v.w;

    __shared__ float rmin[256], rsum[256], rsq[256];
    rmin[tid] = lmin; rsum[tid] = lsum; rsq[tid] = lsq;
    __syncthreads();
    for (int s = 128; s > 0; s >>= 1) {
        if (tid < s) {
            rmin[tid] = fminf(rmin[tid], rmin[tid + s]);
            rsum[tid] += rsum[tid + s];
            rsq[tid]  += rsq[tid + s];
        }
        __syncthreads();
    }
    if (tid == 0) {
        float m = rmin[0], s = rsum[0], q = rsq[0];
        if (isX) { mx[row] = m; sx[row] = s; x2[row] = q - 2.f*m*s + (float)K_DIM*m*m; }
        else     { my[row] = m; sy[row] = s; y2[row] = q - 2.f*m*s + (float)K_DIM*m*m; }
    }
}

// ---------------------------------------------------------------------------
// MFMA GEMM on pre-converted bf16 + cost epilogue (fp16 store).
// 128x128 tile, 4 waves (2x2 of 64x64), BK=32, global_load_lds width 16.
// 2-phase double-buffered K-loop; XCD-swizzled block id.  (verified round 1)
// ---------------------------------------------------------------------------
__global__ __launch_bounds__(256, 4) void gemm_cost_mfma(
    float* __restrict__ gbuf,
    const float* __restrict__ mx, const float* __restrict__ sx, const float* __restrict__ x2,
    const float* __restrict__ my, const float* __restrict__ sy, const float* __restrict__ y2,
    unsigned int* __restrict__ d2max)
{
    __shared__ unsigned short Ash[2][128 * 32];   // 2 x 8 KB
    __shared__ unsigned short Bsh[2][128 * 32];   // 2 x 8 KB
    __shared__ float rmax[256];

    const unsigned char* outb = (const unsigned char*)gbuf;
    const int tid   = threadIdx.x;
    const int lane  = tid & 63;
    const int wave  = tid >> 6;
    const int wi    = wave >> 1;          // 0..1
    const int wj    = wave & 1;           // 0..1
    const int row16 = lane & 15;
    const int quad  = lane >> 4;          // 0..3

    // XCD-aware swizzle (bijective: 1024 blocks, 1024%8==0).
    const int bid0 = blockIdx.y * 16 + blockIdx.x;
    const int bid  = (bid0 & 7) * 128 + (bid0 >> 3);
    const int i0 = (bid >> 4) * 128, j0 = (bid & 15) * 128;

    const int chA = (lane & 3) * 16;       // byte chunk within 64 B row
    const unsigned char* pa[2];
    const unsigned char* pb[2];
    unsigned short* laA[2];
    unsigned short* lbB[2];
    #pragma unroll
    for (int p = 0; p < 2; ++p) {
        const int rt = (p * 4 + wave) * 16 + (lane >> 2);   // row in tile
        pa[p] = outb + xb_off(i0 + rt) + chA;
        pb[p] = outb + yb_off(j0 + rt) + chA;
        laA[p] = &Ash[0][(p * 4 + wave) * 512];
        lbB[p] = &Bsh[0][(p * 4 + wave) * 512];
    }

    f32x4 acc[4][4];
    #pragma unroll
    for (int u = 0; u < 4; ++u)
        #pragma unroll
        for (int v = 0; v < 4; ++v) acc[u][v] = (f32x4){0.f, 0.f, 0.f, 0.f};

#define STAGE(nb) do {                                        \
        gload16(pa[0], laA[0] + (nb) * 4096);                 \
        gload16(pa[1], laA[1] + (nb) * 4096);                 \
        gload16(pb[0], lbB[0] + (nb) * 4096);                 \
        gload16(pb[1], lbB[1] + (nb) * 4096);                 \
        pa[0] += 64; pa[1] += 64; pb[0] += 64; pb[1] += 64;   \
    } while (0)

#define COMPUTE(cb) do {                                                         \
        bf16x8 af[4], bfr[4];                                                    \
        _Pragma("unroll")                                                        \
        for (int t = 0; t < 4; ++t) {                                            \
            af[t]  = lds_frag(&Ash[cb][(wi * 64 + t * 16 + row16) * 32 + quad * 8]); \
            bfr[t] = lds_frag(&Bsh[cb][(wj * 64 + t * 16 + row16) * 32 + quad * 8]); \
        }                                                                        \
        _Pragma("unroll")                                                        \
        for (int ti = 0; ti < 4; ++ti)                                           \
            _Pragma("unroll")                                                    \
            for (int tj = 0; tj < 4; ++tj)                                       \
                acc[ti][tj] = __builtin_amdgcn_mfma_f32_16x16x32_bf16(           \
                    af[ti], bfr[tj], acc[ti][tj], 0, 0, 0);                      \
    } while (0)

    STAGE(0);
    __syncthreads();

#pragma unroll 1
    for (int it = 0; it < 15; ++it) {
        STAGE(1); COMPUTE(0); __syncthreads();
        STAGE(0); COMPUTE(1); __syncthreads();
    }
    STAGE(1); COMPUTE(0); __syncthreads();
    COMPUTE(1);

#undef STAGE
#undef COMPUTE

    // epilogue: C/D layout col=lane&15 (j), row=quad*4+reg (i); store fp16 cost
    _Float16* costh = (_Float16*)gbuf;
    float lmax = 0.0f;
    float myj[4], syj[4], yy[4];
    #pragma unroll
    for (int tj = 0; tj < 4; ++tj) {
        const int j = j0 + wj * 64 + tj * 16 + row16;
        myj[tj] = my[j]; syj[tj] = sy[j]; yy[tj] = y2[j];
    }
    #pragma unroll
    for (int ti = 0; ti < 4; ++ti) {
        #pragma unroll
        for (int reg = 0; reg < 4; ++reg) {
            const int i = i0 + wi * 64 + ti * 16 + quad * 4 + reg;
            const float mxi = mx[i], sxi = sx[i], xxi = x2[i];
            #pragma unroll
            for (int tj = 0; tj < 4; ++tj) {
                const int j = j0 + wj * 64 + tj * 16 + row16;
                float corr = mxi * syj[tj] + myj[tj] * sxi - (float)K_DIM * mxi * myj[tj];
                float d2 = xxi + yy[tj] - 2.0f * acc[ti][tj][reg] + 2.0f * corr;
                d2 = fmaxf(d2, 0.0f);
                lmax = fmaxf(lmax, d2);
                costh[(size_t)i * 4096 + j] = (_Float16)sqrtf(d2);
            }
        }
    }
    rmax[tid] = lmax;
    __syncthreads();
    for (int s = 128; s > 0; s >>= 1) {
        if (tid < s) rmax[tid] = fmaxf(rmax[tid], rmax[tid + s]);
        __syncthreads();
    }
    if (tid == 0) atomicMax(d2max, __float_as_uint(rmax[0]));
}

// ---------------------------------------------------------------------------
// Sinkhorn pass IT (0,1,2). Reads cost fp16, E = exp(-cost*10/cmax) staged in
// LDS (64 KB/block — explicit spill target; registers hold only pr[16]/p[8]).
//   u_j = 1 (IT=0) or N/sigma[IT-1][j]
//   t_r = sum_j E u_j ; w_r = exp(-LAM*(logb + ln t_r))   (w stored at IT=2)
//   sigma[IT][j] += sum_r E w_r   via fp32 atomicAdd (thread owns 8 cols)
// 512 blocks x 256 threads = 2 blocks/CU fully resident (LDS 64.4 KB/block).
// ---------------------------------------------------------------------------
template<int IT>
__global__ __launch_bounds__(256, 2) void sk_pass(
    const float* __restrict__ outbuf, float* __restrict__ sigma,
    float* __restrict__ w,
    const float* __restrict__ params, const unsigned int* __restrict__ d2max)
{
    __shared__ _Float16 Esh[RPB * M_COLS];   // 64 KB
    __shared__ float R[RPB][4];
    __shared__ float W[RPB];

    const int tid  = threadIdx.x;
    const int lane = tid & 63;
    const int wave = tid >> 6;
    const int r0   = blockIdx.x * RPB;
    const float logb = params[1];
    const float invC10 = 10.0f * rsqrtf(__uint_as_float(*d2max));

    float u8[8];
    if constexpr (IT == 0) {
        #pragma unroll
        for (int c = 0; c < 8; ++c) u8[c] = 1.0f;
    } else {
        const float* sg = sigma + (IT - 1) * M_COLS;
        const float4 sa = *(const float4*)(sg + 8 * tid);
        const float4 sb = *(const float4*)(sg + 8 * tid + 4);
        u8[0] = (float)N_ROWS / sa.x; u8[1] = (float)N_ROWS / sa.y;
        u8[2] = (float)N_ROWS / sa.z; u8[3] = (float)N_ROWS / sa.w;
        u8[4] = (float)N_ROWS / sb.x; u8[5] = (float)N_ROWS / sb.y;
        u8[6] = (float)N_ROWS / sb.z; u8[7] = (float)N_ROWS / sb.w;
    }

    // stage + pass A fused: load cost row chunk, exp -> E (fp16, LDS),
    // dot with u -> pr[r]
    const _Float16* Cb = (const _Float16*)outbuf;
    float pr[RPB];
    #pragma unroll
    for (int r = 0; r < RPB; ++r) {
        h8 c = __builtin_bit_cast(h8, *(const uint4*)(Cb + (size_t)(r0 + r) * 4096 + 8 * tid));
        h8 e;
        float s = 0.0f;
        #pragma unroll
        for (int k = 0; k < 8; ++k) {
            _Float16 ek = (_Float16)__expf(-(float)c[k] * invC10);
            e[k] = ek;
            s += (float)ek * u8[k];
        }
        *(uint4*)&Esh[r * M_COLS + 8 * tid] = __builtin_bit_cast(uint4, e);
        pr[r] = s;
    }

    #pragma unroll
    for (int r = 0; r < RPB; ++r)
        #pragma unroll
        for (int off = 32; off > 0; off >>= 1)
            pr[r] += __shfl_xor(pr[r], off, 64);

    if (lane == 0)
        #pragma unroll
        for (int r = 0; r < RPB; ++r) R[r][wave] = pr[r];
    __syncthreads();
    if (tid < RPB) {
        float t = R[tid][0] + R[tid][1] + R[tid][2] + R[tid][3];
        float wr = __expf(-LAM * (logb + __logf(t)));
        W[tid] = wr;
        if constexpr (IT == 2) w[r0 + tid] = wr;
    }
    __syncthreads();

    // pass B: column partials from LDS -> fp32 atomicAdd into sigma[IT]
    float p[8] = {0.f, 0.f, 0.f, 0.f, 0.f, 0.f, 0.f, 0.f};
    #pragma unroll
    for (int r = 0; r < RPB; ++r) {
        h8 e = __builtin_bit_cast(h8, *(const uint4*)&Esh[r * M_COLS + 8 * tid]);
        const float wr = W[r];
        #pragma unroll
        for (int k = 0; k < 8; ++k) p[k] += (float)e[k] * wr;
    }
    float* sg1 = sigma + IT * M_COLS;
    #pragma unroll
    for (int c = 0; c < 8; ++c) atomicAdd(&sg1[8 * tid + c], p[c]);
}

// ---------------------------------------------------------------------------
// flow = E * w_r * u_j / (N*M)  (in-place: fp16 cost rows -> fp32 flow rows)
// dist += sum cn * flow,  cn = cost/cmax;  u_j = N/sigma2_j
// Cost rows staged in LDS (64 KB); ONE barrier (drains loads), then per-row
// compute + store. Registers stay tiny — no scratch spill.
// ---------------------------------------------------------------------------
__global__ __launch_bounds__(256, 2) void flow_dist(
    float* __restrict__ outbuf, const float* __restrict__ w,
    const float* __restrict__ sigma2, const unsigned int* __restrict__ d2max,
    float* __restrict__ dist)
{
    __shared__ _Float16 Csh[RPB * M_COLS];   // 64 KB
    __shared__ float W[RPB];
    __shared__ float red[256];

    const int tid = threadIdx.x;
    const int r0  = blockIdx.x * RPB;
    const float invNM = 1.0f / ((float)N_ROWS * (float)M_COLS);
    const float invC10 = 10.0f * rsqrtf(__uint_as_float(*d2max));
    const float inv01  = 0.1f * invC10;          // = 1/cmax
    const _Float16* Cb = (const _Float16*)outbuf;

    #pragma unroll
    for (int r = 0; r < RPB; ++r) {
        uint4 cv = *(const uint4*)(Cb + (size_t)(r0 + r) * 4096 + 8 * tid);
        *(uint4*)&Csh[r * M_COLS + 8 * tid] = cv;
    }

    if (tid < RPB) W[tid] = w[r0 + tid];

    const float4 sA = *(const float4*)(sigma2 + 8 * tid);
    const float4 sB = *(const float4*)(sigma2 + 8 * tid + 4);
    float u8[8];
    u8[0] = (float)N_ROWS / sA.x; u8[1] = (float)N_ROWS / sA.y;
    u8[2] = (float)N_ROWS / sA.z; u8[3] = (float)N_ROWS / sA.w;
    u8[4] = (float)N_ROWS / sB.x; u8[5] = (float)N_ROWS / sB.y;
    u8[6] = (float)N_ROWS / sB.z; u8[7] = (float)N_ROWS / sB.w;

    __syncthreads();   // all cost loads landed in LDS + W visible; stores safe

    float local = 0.0f;
    #pragma unroll
    for (int r = 0; r < RPB; ++r) {
        h8 c = __builtin_bit_cast(h8, *(const uint4*)&Csh[r * M_COLS + 8 * tid]);
        const float wr = W[r];
        float fl[8];
        #pragma unroll
        for (int k = 0; k < 8; ++k) {
            float cst = (float)c[k];
            float e = __expf(-cst * invC10);
            float o = e * wr * u8[k] * invNM;
            fl[k] = o;
            local += (cst * inv01) * o;
        }
        float4 o0 = {fl[0], fl[1], fl[2], fl[3]};
        float4 o1 = {fl[4], fl[5], fl[6], fl[7]};
        float* frow = outbuf + (size_t)(r0 + r) * M_COLS + 8 * tid;
        *(float4*)frow = o0;
        *(float4*)(frow + 4) = o1;
    }

    red[tid] = local;
    __syncthreads();
    for (int s = 128; s > 0; s >>= 1) {
        if (tid < s) red[tid] += red[tid + s];
        __syncthreads();
    }
    if (tid == 0) atomicAdd(dist, red[0]);
}

// ---------------------------------------------------------------------------
extern "C" void kernel_launch(void* const* d_in, const int* in_sizes, int n_in,
                              void* d_out, int out_size, void* d_ws, size_t ws_size,
                              hipStream_t stream)
{
    const float* x     = (const float*)d_in[0];
    const float* y     = (const float*)d_in[1];
    const int*   iters = (const int*)d_in[2];
    const int*   ipe   = (const int*)d_in[3];
    float* out = (float*)d_out;
    float* ws  = (float*)d_ws;

    // ws layout (floats)
    float*        params = ws;                       // [0]=rho [1]=logb
    unsigned int* d2max  = (unsigned int*)(ws + 8);
    float* w     = ws + 16;                          // 8192
    float* sigma = w + N_ROWS;                       // 3 * 2048 (zeroed by rowstats blk0)
    float* mx = sigma + 3 * M_COLS;                  // 8192
    float* sx = mx + N_ROWS;                         // 8192
    float* x2 = sx + N_ROWS;                         // 8192
    float* my = x2 + N_ROWS;                         // 2048
    float* sy = my + M_COLS;                         // 2048
    float* y2 = sy + M_COLS;                         // 2048

    float* dist = out + NM;

    rowstats_cvt<<<N_ROWS + M_COLS, 256, 0, stream>>>(
        x, y, (unsigned char*)out, iters, ipe, params, sigma, d2max, dist,
        mx, sx, x2, my, sy, y2);
    gemm_cost_mfma<<<dim3(M_COLS / 128, N_ROWS / 128), 256, 0, stream>>>(
        out, mx, sx, x2, my, sy, y2, d2max);

    sk_pass<0><<<SKB, 256, 0, stream>>>(out, sigma, w, params, d2max);
    sk_pass<1><<<SKB, 256, 0, stream>>>(out, sigma, w, params, d2max);
    sk_pass<2><<<SKB, 256, 0, stream>>>(out, sigma, w, params, d2max);

    flow_dist<<<SKB, 256, 0, stream>>>(out, w, sigma + 2 * M_COLS, d2max, dist);
}

// Round 5
// 214.826 us; speedup vs baseline: 2.4454x; 2.4187x over previous
//
#include <hip/hip_runtime.h>
#include <math.h>

// Problem constants
#define N_ROWS 8192
#define M_COLS 2048
#define K_DIM  1024
#define NM     ((size_t)N_ROWS * M_COLS)

#define LAM       0.9090909090909091f         // GAMMA/(GAMMA+EPS)
#define LOG_M     7.624618986159398f          // log(2048)

#define SKB 512                                // sinkhorn blocks
#define RPB (N_ROWS / SKB)                     // 16 rows per block

typedef __bf16 bf16x8 __attribute__((ext_vector_type(8)));
typedef float  f32x4  __attribute__((ext_vector_type(4)));
typedef unsigned short u16x8 __attribute__((ext_vector_type(8)));
typedef _Float16 h8 __attribute__((ext_vector_type(8)));

// d_out memory map (64 MB):
//   row r (r<8192): bytes [r*8192, r*8192+4096)  = cost fp16 row r (2048 halves)
//                   bytes [r*8192+4096, r*8192+8192) = "hole"
//   Xb bf16 row i (16 MB): hole i>>1, slot i&1  -> byte (i>>1)*8192 + 4096 + (i&1)*2048
//   Yb bf16 row j ( 4 MB): hole 4096+(j>>1)     -> byte 32MB + (j>>1)*8192 + 4096 + (j&1)*2048
// GEMM writes cost into even chunks while reading Xb/Yb from odd chunks (disjoint).
//
// ATOMICS LESSON (round 4): 1M same-line fp32 atomicAdds onto 2048 addresses =
// ~120 us of serialized memory-side RMWs (WRITE_SIZE showed exactly 32B/atomic).
// Column sums therefore go: regular stores -> gpart[512][2048] fp32 -> 64-block
// reduce with depth-8 atomics.

static __device__ __forceinline__ size_t xb_off(int i) {
    return ((size_t)(i >> 1) << 13) + 4096 + ((size_t)(i & 1) << 11);
}
static __device__ __forceinline__ size_t yb_off(int j) {
    return ((size_t)1 << 25) + ((size_t)(j >> 1) << 13) + 4096 + ((size_t)(j & 1) << 11);
}

// ---------------------------------------------------------------------------
// fp32 pair -> packed bf16 (RNE)
// ---------------------------------------------------------------------------
static __device__ __forceinline__ unsigned pk_bf16(float a, float b) {
#if __has_builtin(__builtin_amdgcn_cvt_pk_bf16_f32)
    typedef __bf16 bf16x2 __attribute__((ext_vector_type(2)));
    bf16x2 r = __builtin_amdgcn_cvt_pk_bf16_f32(a, b);
    return __builtin_bit_cast(unsigned, r);
#else
    unsigned ua = __float_as_uint(a), ub = __float_as_uint(b);
    ua += 0x7FFFu + ((ua >> 16) & 1u);
    ub += 0x7FFFu + ((ub >> 16) & 1u);
    return (ua >> 16) | (ub & 0xFFFF0000u);
#endif
}

static __device__ __forceinline__ bf16x8 lds_frag(const unsigned short* p) {
    return __builtin_bit_cast(bf16x8, *(const u16x8*)p);
}

static __device__ __forceinline__ void gload16(const void* g, void* l) {
    __builtin_amdgcn_global_load_lds(
        (const __attribute__((address_space(1))) unsigned int*)g,
        (__attribute__((address_space(3))) unsigned int*)l, 16, 0, 0);
}

// ---------------------------------------------------------------------------
// per-row stats (min, sum, ||a-min||^2) + bf16 conversion into d_out holes.
// blocks 0..8191 = X rows; 8192..10239 = Y rows. 256 thr, 4 cols each.
// Block 0 additionally does init (params, sigma=0, d2max=0, dist=0).
// ---------------------------------------------------------------------------
__global__ __launch_bounds__(256) void rowstats_cvt(
    const float* __restrict__ X, const float* __restrict__ Y,
    unsigned char* __restrict__ outb,
    const int* __restrict__ iters, const int* __restrict__ ipe,
    float* __restrict__ params, float* __restrict__ sigma,
    unsigned int* __restrict__ d2max, float* __restrict__ dist,
    float* __restrict__ mx, float* __restrict__ sx, float* __restrict__ x2,
    float* __restrict__ my, float* __restrict__ sy, float* __restrict__ y2)
{
    const int b = blockIdx.x, tid = threadIdx.x;

    if (b == 0) {
        #pragma unroll 1
        for (int i = tid; i < 3 * M_COLS; i += 256) sigma[i] = 0.0f;
        if (tid == 0) {
            float ramp = 10.0f * (float)ipe[0];
            float rho;
            if (ramp == 0.0f) {
                rho = 1.1f;
            } else {
                float cur = fminf(fmaxf((float)iters[0], 0.0f), ramp);
                float phase = 1.0f - cur / ramp;
                rho = expf(-5.0f * phase * phase) + 0.1f;
            }
            rho = fminf(rho, 1.0f);
            params[0] = rho;
            params[1] = logf(rho) - LOG_M;   // logb = log(rho/M)
            *d2max = 0u;
            *dist = 0.0f;
        }
    }

    const bool isX = b < N_ROWS;
    const int row = isX ? b : b - N_ROWS;
    const float* src = isX ? (X + (size_t)row * K_DIM) : (Y + (size_t)row * K_DIM);
    const float4 v = ((const float4*)src)[tid];

    // bf16 convert into hole
    uint2 p; p.x = pk_bf16(v.x, v.y); p.y = pk_bf16(v.z, v.w);
    size_t off = isX ? xb_off(row) : yb_off(row);
    *(uint2*)(outb + off + (size_t)tid * 8) = p;

    float lmin = fminf(fminf(v.x, v.y), fminf(v.z, v.w));
    float lsum = v.x + v.y + v.z + v.w;
    float lsq  = v.x*v.x + v.y*v.y + v.z*v.z + v.w*v.w;

    __shared__ float rmin[256], rsum[256], rsq[256];
    rmin[tid] = lmin; rsum[tid] = lsum; rsq[tid] = lsq;
    __syncthreads();
    for (int s = 128; s > 0; s >>= 1) {
        if (tid < s) {
            rmin[tid] = fminf(rmin[tid], rmin[tid + s]);
            rsum[tid] += rsum[tid + s];
            rsq[tid]  += rsq[tid + s];
        }
        __syncthreads();
    }
    if (tid == 0) {
        float m = rmin[0], s = rsum[0], q = rsq[0];
        if (isX) { mx[row] = m; sx[row] = s; x2[row] = q - 2.f*m*s + (float)K_DIM*m*m; }
        else     { my[row] = m; sy[row] = s; y2[row] = q - 2.f*m*s + (float)K_DIM*m*m; }
    }
}

// ---------------------------------------------------------------------------
// MFMA GEMM on pre-converted bf16 + cost epilogue (fp16 store).
// 128x128 tile, 4 waves (2x2 of 64x64), BK=32, global_load_lds width 16.
// 2-phase double-buffered K-loop; XCD-swizzled block id.  (verified round 1)
// ---------------------------------------------------------------------------
__global__ __launch_bounds__(256, 4) void gemm_cost_mfma(
    float* __restrict__ gbuf,
    const float* __restrict__ mx, const float* __restrict__ sx, const float* __restrict__ x2,
    const float* __restrict__ my, const float* __restrict__ sy, const float* __restrict__ y2,
    unsigned int* __restrict__ d2max)
{
    __shared__ unsigned short Ash[2][128 * 32];   // 2 x 8 KB
    __shared__ unsigned short Bsh[2][128 * 32];   // 2 x 8 KB
    __shared__ float rmax[256];

    const unsigned char* outb = (const unsigned char*)gbuf;
    const int tid   = threadIdx.x;
    const int lane  = tid & 63;
    const int wave  = tid >> 6;
    const int wi    = wave >> 1;          // 0..1
    const int wj    = wave & 1;           // 0..1
    const int row16 = lane & 15;
    const int quad  = lane >> 4;          // 0..3

    // XCD-aware swizzle (bijective: 1024 blocks, 1024%8==0).
    const int bid0 = blockIdx.y * 16 + blockIdx.x;
    const int bid  = (bid0 & 7) * 128 + (bid0 >> 3);
    const int i0 = (bid >> 4) * 128, j0 = (bid & 15) * 128;

    const int chA = (lane & 3) * 16;       // byte chunk within 64 B row
    const unsigned char* pa[2];
    const unsigned char* pb[2];
    unsigned short* laA[2];
    unsigned short* lbB[2];
    #pragma unroll
    for (int p = 0; p < 2; ++p) {
        const int rt = (p * 4 + wave) * 16 + (lane >> 2);   // row in tile
        pa[p] = outb + xb_off(i0 + rt) + chA;
        pb[p] = outb + yb_off(j0 + rt) + chA;
        laA[p] = &Ash[0][(p * 4 + wave) * 512];
        lbB[p] = &Bsh[0][(p * 4 + wave) * 512];
    }

    f32x4 acc[4][4];
    #pragma unroll
    for (int u = 0; u < 4; ++u)
        #pragma unroll
        for (int v = 0; v < 4; ++v) acc[u][v] = (f32x4){0.f, 0.f, 0.f, 0.f};

#define STAGE(nb) do {                                        \
        gload16(pa[0], laA[0] + (nb) * 4096);                 \
        gload16(pa[1], laA[1] + (nb) * 4096);                 \
        gload16(pb[0], lbB[0] + (nb) * 4096);                 \
        gload16(pb[1], lbB[1] + (nb) * 4096);                 \
        pa[0] += 64; pa[1] += 64; pb[0] += 64; pb[1] += 64;   \
    } while (0)

#define COMPUTE(cb) do {                                                         \
        bf16x8 af[4], bfr[4];                                                    \
        _Pragma("unroll")                                                        \
        for (int t = 0; t < 4; ++t) {                                            \
            af[t]  = lds_frag(&Ash[cb][(wi * 64 + t * 16 + row16) * 32 + quad * 8]); \
            bfr[t] = lds_frag(&Bsh[cb][(wj * 64 + t * 16 + row16) * 32 + quad * 8]); \
        }                                                                        \
        _Pragma("unroll")                                                        \
        for (int ti = 0; ti < 4; ++ti)                                           \
            _Pragma("unroll")                                                    \
            for (int tj = 0; tj < 4; ++tj)                                       \
                acc[ti][tj] = __builtin_amdgcn_mfma_f32_16x16x32_bf16(           \
                    af[ti], bfr[tj], acc[ti][tj], 0, 0, 0);                      \
    } while (0)

    STAGE(0);
    __syncthreads();

#pragma unroll 1
    for (int it = 0; it < 15; ++it) {
        STAGE(1); COMPUTE(0); __syncthreads();
        STAGE(0); COMPUTE(1); __syncthreads();
    }
    STAGE(1); COMPUTE(0); __syncthreads();
    COMPUTE(1);

#undef STAGE
#undef COMPUTE

    // epilogue: C/D layout col=lane&15 (j), row=quad*4+reg (i); store fp16 cost
    _Float16* costh = (_Float16*)gbuf;
    float lmax = 0.0f;
    float myj[4], syj[4], yy[4];
    #pragma unroll
    for (int tj = 0; tj < 4; ++tj) {
        const int j = j0 + wj * 64 + tj * 16 + row16;
        myj[tj] = my[j]; syj[tj] = sy[j]; yy[tj] = y2[j];
    }
    #pragma unroll
    for (int ti = 0; ti < 4; ++ti) {
        #pragma unroll
        for (int reg = 0; reg < 4; ++reg) {
            const int i = i0 + wi * 64 + ti * 16 + quad * 4 + reg;
            const float mxi = mx[i], sxi = sx[i], xxi = x2[i];
            #pragma unroll
            for (int tj = 0; tj < 4; ++tj) {
                const int j = j0 + wj * 64 + tj * 16 + row16;
                float corr = mxi * syj[tj] + myj[tj] * sxi - (float)K_DIM * mxi * myj[tj];
                float d2 = xxi + yy[tj] - 2.0f * acc[ti][tj][reg] + 2.0f * corr;
                d2 = fmaxf(d2, 0.0f);
                lmax = fmaxf(lmax, d2);
                costh[(size_t)i * 4096 + j] = (_Float16)sqrtf(d2);
            }
        }
    }
    rmax[tid] = lmax;
    __syncthreads();
    for (int s = 128; s > 0; s >>= 1) {
        if (tid < s) rmax[tid] = fmaxf(rmax[tid], rmax[tid + s]);
        __syncthreads();
    }
    if (tid == 0) atomicMax(d2max, __float_as_uint(rmax[0]));
}

// ---------------------------------------------------------------------------
// Sinkhorn pass IT (0,1,2). Reads cost fp16, E = exp(-cost*10/cmax) staged in
// LDS (64 KB/block).
//   u_j = 1 (IT=0) or N/sigma[IT-1][j]
//   t_r = sum_j E u_j ; w_r = exp(-LAM*(logb + ln t_r))   (w stored at IT=2)
//   column partials -> REGULAR stores into gpart[block][2048] (no atomics!)
// 512 blocks x 256 threads = 2 blocks/CU resident (LDS 64.4 KB/block).
// ---------------------------------------------------------------------------
template<int IT>
__global__ __launch_bounds__(256, 2) void sk_pass(
    const float* __restrict__ outbuf, const float* __restrict__ sigma,
    float* __restrict__ gpart, float* __restrict__ w,
    const float* __restrict__ params, const unsigned int* __restrict__ d2max)
{
    __shared__ _Float16 Esh[RPB * M_COLS];   // 64 KB
    __shared__ float R[RPB][4];
    __shared__ float W[RPB];

    const int tid  = threadIdx.x;
    const int lane = tid & 63;
    const int wave = tid >> 6;
    const int r0   = blockIdx.x * RPB;
    const float logb = params[1];
    const float invC10 = 10.0f * rsqrtf(__uint_as_float(*d2max));

    float u8[8];
    if constexpr (IT == 0) {
        #pragma unroll
        for (int c = 0; c < 8; ++c) u8[c] = 1.0f;
    } else {
        const float* sg = sigma + (IT - 1) * M_COLS;
        const float4 sa = *(const float4*)(sg + 8 * tid);
        const float4 sb = *(const float4*)(sg + 8 * tid + 4);
        u8[0] = (float)N_ROWS / sa.x; u8[1] = (float)N_ROWS / sa.y;
        u8[2] = (float)N_ROWS / sa.z; u8[3] = (float)N_ROWS / sa.w;
        u8[4] = (float)N_ROWS / sb.x; u8[5] = (float)N_ROWS / sb.y;
        u8[6] = (float)N_ROWS / sb.z; u8[7] = (float)N_ROWS / sb.w;
    }

    // stage + pass A fused: load cost row chunk, exp -> E (fp16, LDS),
    // dot with u -> pr[r]
    const _Float16* Cb = (const _Float16*)outbuf;
    float pr[RPB];
    #pragma unroll
    for (int r = 0; r < RPB; ++r) {
        h8 c = __builtin_bit_cast(h8, *(const uint4*)(Cb + (size_t)(r0 + r) * 4096 + 8 * tid));
        h8 e;
        float s = 0.0f;
        #pragma unroll
        for (int k = 0; k < 8; ++k) {
            _Float16 ek = (_Float16)__expf(-(float)c[k] * invC10);
            e[k] = ek;
            s += (float)ek * u8[k];
        }
        *(uint4*)&Esh[r * M_COLS + 8 * tid] = __builtin_bit_cast(uint4, e);
        pr[r] = s;
    }

    #pragma unroll
    for (int r = 0; r < RPB; ++r)
        #pragma unroll
        for (int off = 32; off > 0; off >>= 1)
            pr[r] += __shfl_xor(pr[r], off, 64);

    if (lane == 0)
        #pragma unroll
        for (int r = 0; r < RPB; ++r) R[r][wave] = pr[r];
    __syncthreads();
    if (tid < RPB) {
        float t = R[tid][0] + R[tid][1] + R[tid][2] + R[tid][3];
        float wr = __expf(-LAM * (logb + __logf(t)));
        W[tid] = wr;
        if constexpr (IT == 2) w[r0 + tid] = wr;
    }
    __syncthreads();

    // pass B: column partials from LDS -> regular coalesced stores to gpart
    float p[8] = {0.f, 0.f, 0.f, 0.f, 0.f, 0.f, 0.f, 0.f};
    #pragma unroll
    for (int r = 0; r < RPB; ++r) {
        h8 e = __builtin_bit_cast(h8, *(const uint4*)&Esh[r * M_COLS + 8 * tid]);
        const float wr = W[r];
        #pragma unroll
        for (int k = 0; k < 8; ++k) p[k] += (float)e[k] * wr;
    }
    float* gp = gpart + (size_t)blockIdx.x * M_COLS + 8 * tid;
    float4 p0 = {p[0], p[1], p[2], p[3]};
    float4 p1 = {p[4], p[5], p[6], p[7]};
    *(float4*)gp = p0;
    *(float4*)(gp + 4) = p1;
}

// ---------------------------------------------------------------------------
// sigma[col] += sum over a 64-row slab of gpart.  64 blocks (8 col-groups x
// 8 row-slabs): atomic depth per address = 8 only.
// ---------------------------------------------------------------------------
__global__ __launch_bounds__(256) void sk_gred(
    const float* __restrict__ gpart, float* __restrict__ sigma)
{
    const int col = (blockIdx.x & 7) * 256 + threadIdx.x;
    const int b0  = (blockIdx.x >> 3) * (SKB / 8);
    float s = 0.0f;
    #pragma unroll 8
    for (int b = 0; b < SKB / 8; ++b)
        s += gpart[(size_t)(b0 + b) * M_COLS + col];
    atomicAdd(&sigma[col], s);
}

// ---------------------------------------------------------------------------
// flow = E * w_r * u_j / (N*M)  (in-place: fp16 cost rows -> fp32 flow rows)
// dist += sum cn * flow,  cn = cost/cmax;  u_j = N/sigma2_j
// Cost rows staged in LDS (64 KB); ONE barrier, then per-row compute + store.
// ---------------------------------------------------------------------------
__global__ __launch_bounds__(256, 2) void flow_dist(
    float* __restrict__ outbuf, const float* __restrict__ w,
    const float* __restrict__ sigma2, const unsigned int* __restrict__ d2max,
    float* __restrict__ dist)
{
    __shared__ _Float16 Csh[RPB * M_COLS];   // 64 KB
    __shared__ float W[RPB];
    __shared__ float red[256];

    const int tid = threadIdx.x;
    const int r0  = blockIdx.x * RPB;
    const float invNM = 1.0f / ((float)N_ROWS * (float)M_COLS);
    const float invC10 = 10.0f * rsqrtf(__uint_as_float(*d2max));
    const float inv01  = 0.1f * invC10;          // = 1/cmax
    const _Float16* Cb = (const _Float16*)outbuf;

    #pragma unroll
    for (int r = 0; r < RPB; ++r) {
        uint4 cv = *(const uint4*)(Cb + (size_t)(r0 + r) * 4096 + 8 * tid);
        *(uint4*)&Csh[r * M_COLS + 8 * tid] = cv;
    }

    if (tid < RPB) W[tid] = w[r0 + tid];

    const float4 sA = *(const float4*)(sigma2 + 8 * tid);
    const float4 sB = *(const float4*)(sigma2 + 8 * tid + 4);
    float u8[8];
    u8[0] = (float)N_ROWS / sA.x; u8[1] = (float)N_ROWS / sA.y;
    u8[2] = (float)N_ROWS / sA.z; u8[3] = (float)N_ROWS / sA.w;
    u8[4] = (float)N_ROWS / sB.x; u8[5] = (float)N_ROWS / sB.y;
    u8[6] = (float)N_ROWS / sB.z; u8[7] = (float)N_ROWS / sB.w;

    __syncthreads();   // all cost loads landed in LDS + W visible; stores safe

    float local = 0.0f;
    #pragma unroll
    for (int r = 0; r < RPB; ++r) {
        h8 c = __builtin_bit_cast(h8, *(const uint4*)&Csh[r * M_COLS + 8 * tid]);
        const float wr = W[r];
        float fl[8];
        #pragma unroll
        for (int k = 0; k < 8; ++k) {
            float cst = (float)c[k];
            float e = __expf(-cst * invC10);
            float o = e * wr * u8[k] * invNM;
            fl[k] = o;
            local += (cst * inv01) * o;
        }
        float4 o0 = {fl[0], fl[1], fl[2], fl[3]};
        float4 o1 = {fl[4], fl[5], fl[6], fl[7]};
        float* frow = outbuf + (size_t)(r0 + r) * M_COLS + 8 * tid;
        *(float4*)frow = o0;
        *(float4*)(frow + 4) = o1;
    }

    red[tid] = local;
    __syncthreads();
    for (int s = 128; s > 0; s >>= 1) {
        if (tid < s) red[tid] += red[tid + s];
        __syncthreads();
    }
    if (tid == 0) atomicAdd(dist, red[0]);
}

// ---------------------------------------------------------------------------
extern "C" void kernel_launch(void* const* d_in, const int* in_sizes, int n_in,
                              void* d_out, int out_size, void* d_ws, size_t ws_size,
                              hipStream_t stream)
{
    const float* x     = (const float*)d_in[0];
    const float* y     = (const float*)d_in[1];
    const int*   iters = (const int*)d_in[2];
    const int*   ipe   = (const int*)d_in[3];
    float* out = (float*)d_out;
    float* ws  = (float*)d_ws;

    // ws layout (floats): ~4.2 MB total
    float*        params = ws;                       // [0]=rho [1]=logb
    unsigned int* d2max  = (unsigned int*)(ws + 8);
    float* w     = ws + 16;                          // 8192
    float* sigma = w + N_ROWS;                       // 3 * 2048 (zeroed by rowstats blk0)
    float* mx = sigma + 3 * M_COLS;                  // 8192
    float* sx = mx + N_ROWS;                         // 8192
    float* x2 = sx + N_ROWS;                         // 8192
    float* my = x2 + N_ROWS;                         // 2048
    float* sy = my + M_COLS;                         // 2048
    float* y2 = sy + M_COLS;                         // 2048
    float* gpart = y2 + M_COLS;                      // 512*2048 fp32 = 4 MB

    float* sigma0 = sigma;
    float* sigma1 = sigma + M_COLS;
    float* sigma2 = sigma + 2 * M_COLS;

    float* dist = out + NM;

    rowstats_cvt<<<N_ROWS + M_COLS, 256, 0, stream>>>(
        x, y, (unsigned char*)out, iters, ipe, params, sigma, d2max, dist,
        mx, sx, x2, my, sy, y2);
    gemm_cost_mfma<<<dim3(M_COLS / 128, N_ROWS / 128), 256, 0, stream>>>(
        out, mx, sx, x2, my, sy, y2, d2max);

    sk_pass<0><<<SKB, 256, 0, stream>>>(out, sigma, gpart, w, params, d2max);
    sk_gred<<<64, 256, 0, stream>>>(gpart, sigma0);
    sk_pass<1><<<SKB, 256, 0, stream>>>(out, sigma, gpart, w, params, d2max);
    sk_gred<<<64, 256, 0, stream>>>(gpart, sigma1);
    sk_pass<2><<<SKB, 256, 0, stream>>>(out, sigma, gpart, w, params, d2max);
    sk_gred<<<64, 256, 0, stream>>>(gpart, sigma2);

    flow_dist<<<SKB, 256, 0, stream>>>(out, w, sigma2, d2max, dist);
}